// Round 5
// baseline (302.524 us; speedup 1.0000x reference)
//
#include <hip/hip_runtime.h>
#include <hip/hip_cooperative_groups.h>
#include <hip/hip_fp8.h>
#include <math.h>

typedef float v4f __attribute__((ext_vector_type(4)));

static constexpr int Bn = 8192;   // batch
static constexpr int Hn = 768;    // hidden
static constexpr float invB = 1.0f / 8192.0f;

__device__ __forceinline__ unsigned char cvt_e4m3(float x) {
    __hip_fp8_e4m3 t(x);          // OCP e4m3fn, RNE + satfinite
    return t.__x;
}

__device__ __forceinline__ unsigned pack4_e4m3(float4 f) {
    return (unsigned)cvt_e4m3(f.x)
         | ((unsigned)cvt_e4m3(f.y) << 8)
         | ((unsigned)cvt_e4m3(f.z) << 16)
         | ((unsigned)cvt_e4m3(f.w) << 24);
}

// tanh(x) = 1 - 2/(exp(2x)+1)
__device__ __forceinline__ float fast_tanh(float x) {
    float xc = fminf(fmaxf(x, -15.0f), 15.0f);
    float e = __expf(2.0f * xc);
    float r = __builtin_amdgcn_rcpf(e + 1.0f);
    return 1.0f - 2.0f * r;
}

// ============================================================================
// SINGLE cooperative kernel. 256 blocks x 1024 thr (1 block/CU, 4 waves/SIMD).
//   phase 0: grid-wide: zero accumulators + W fp32->fp8 (each block 1/256);
//            __threadfence + grid.sync (device-scope, cross-XCD safe)
//   phase 1: A fp32 strip (32 rows) -> fp8 -> LDS Xs (XOR slot c ^ (row&15))
//   phase 2: layer-1 BOTH branches, W streamed L2->regs
//   phase 3: tanh -> fp8 pack -> h1m to Hm, h1v to Xs (A dead)
//   phase 4: layer-2 BOTH branches
//   phase 5: CLUB epilogue + last-block finalize
// Body of phases 1-5 is identical to round-4 (known-correct).
// ============================================================================
__launch_bounds__(1024, 4)
__global__ void club_all(const float* __restrict__ A_g, const float* __restrict__ mb,
                         const float* __restrict__ W1m_f, const float* __restrict__ W2m_f,
                         const float* __restrict__ W1v_f, const float* __restrict__ W2v_f,
                         const float* __restrict__ b1m, const float* __restrict__ b1v,
                         const float* __restrict__ b2m, const float* __restrict__ b2v,
                         unsigned char* __restrict__ W1m8, unsigned char* __restrict__ W2m8,
                         unsigned char* __restrict__ W1v8, unsigned char* __restrict__ W2v8,
                         float* __restrict__ cs, float* __restrict__ cs2,
                         float* __restrict__ siv, float* __restrict__ sivmu,
                         float* __restrict__ accum, float* __restrict__ outp) {
    __shared__ __align__(16) unsigned char Hm[32 * 768];   // 24 KB: h1m strip
    __shared__ __align__(16) unsigned char Xs[32 * 768];   // 24 KB: A-fp8, then h1v
    const int t = threadIdx.x;
    const int strip0 = blockIdx.x * 32;    // batch strip

    // ---- phase 0: grid-cooperative prep (zero + W convert), then grid sync
    {
        const int gtid = blockIdx.x * 1024 + t;        // 262144 threads
        if (gtid < 4 * Hn + 8) cs[gtid] = 0.0f;        // cs|cs2|siv|sivmu|accum contiguous
        constexpr int W4 = Hn * Hn / 4;                // 147456 float4 units per matrix
        for (int i = gtid; i < 4 * W4; i += 256 * 1024) {
            int w = i / W4, j = i - w * W4;
            const float* s = (w == 0) ? W1m_f : (w == 1) ? W2m_f : (w == 2) ? W1v_f : W2v_f;
            unsigned char* d = (w == 0) ? W1m8 : (w == 1) ? W2m8 : (w == 2) ? W1v8 : W2v8;
            float4 v = ((const float4*)s)[j];
            ((unsigned*)d)[j] = pack4_e4m3(v);
        }
    }
    __threadfence();
    cooperative_groups::this_grid().sync();

    // ---- phase 1: stage + convert A strip (32 x 768 fp32 -> fp8), 1536 16B chunks
    for (int c = t; c < 1536; c += 1024) {
        const int row = c / 48, cc = c - row * 48;
        const float* src = A_g + (size_t)(strip0 + row) * Hn + cc * 16;
        float4 f0 = *(const float4*)(src + 0);
        float4 f1 = *(const float4*)(src + 4);
        float4 f2 = *(const float4*)(src + 8);
        float4 f3 = *(const float4*)(src + 12);
        uint4 p;
        p.x = pack4_e4m3(f0); p.y = pack4_e4m3(f1);
        p.z = pack4_e4m3(f2); p.w = pack4_e4m3(f3);
        *(uint4*)&Xs[row * 768 + ((cc ^ (row & 15)) << 4)] = p;
    }
    __syncthreads();

    const int w = t >> 6, lane = t & 63;
    const int lr = lane & 15, quad = lane >> 4;
    const int wc0 = w * 48;                // wave's 48 hidden cols

    // ---- phase 2: layer-1 dual-branch K-loop
    v4f am[3][2] = {}, av[3][2] = {};      // [ct][rt]; D-row=hidden(quad*4+r), D-col=batch(lr)
    {
        const unsigned char* __restrict__ pWm = W1m8 + (size_t)(wc0 + lr) * Hn + quad * 16;
        const unsigned char* __restrict__ pWv = W1v8 + (size_t)(wc0 + lr) * Hn + quad * 16;
#pragma unroll
        for (int ms = 0; ms < 12; ++ms) {
            ulonglong2 wmf[3], wvf[3], af[2];
#pragma unroll
            for (int ct = 0; ct < 3; ++ct) {
                wmf[ct] = *(const ulonglong2*)(pWm + ct * (16 * Hn) + ms * 64);
                wvf[ct] = *(const ulonglong2*)(pWv + ct * (16 * Hn) + ms * 64);
            }
#pragma unroll
            for (int rt = 0; rt < 2; ++rt) {
                const int row_ = rt * 16 + lr;
                const int k_ = ms * 4 + quad;
                af[rt] = *(const ulonglong2*)&Xs[row_ * 768 + ((k_ ^ (row_ & 15)) << 4)];
            }
#pragma unroll
            for (int ct = 0; ct < 3; ++ct)
#pragma unroll
                for (int rt = 0; rt < 2; ++rt) {
                    am[ct][rt] = __builtin_amdgcn_mfma_f32_16x16x32_fp8_fp8((long)wmf[ct].x, (long)af[rt].x, am[ct][rt], 0, 0, 0);
                    av[ct][rt] = __builtin_amdgcn_mfma_f32_16x16x32_fp8_fp8((long)wvf[ct].x, (long)af[rt].x, av[ct][rt], 0, 0, 0);
                }
#pragma unroll
            for (int ct = 0; ct < 3; ++ct)
#pragma unroll
                for (int rt = 0; rt < 2; ++rt) {
                    am[ct][rt] = __builtin_amdgcn_mfma_f32_16x16x32_fp8_fp8((long)wmf[ct].y, (long)af[rt].y, am[ct][rt], 0, 0, 0);
                    av[ct][rt] = __builtin_amdgcn_mfma_f32_16x16x32_fp8_fp8((long)wvf[ct].y, (long)af[rt].y, av[ct][rt], 0, 0, 0);
                }
        }
    }

    __syncthreads();   // all waves done reading Xs (A)

    // ---- phase 3: tanh + fp8 pack -> Hm (mu), Xs (logvar)
#pragma unroll
    for (int ct = 0; ct < 3; ++ct) {
        const float4 bbm = *(const float4*)&b1m[wc0 + ct * 16 + quad * 4];
        const float4 bbv = *(const float4*)&b1v[wc0 + ct * 16 + quad * 4];
        const int cc = w * 3 + ct;         // 16B chunk of these 4 hidden cols (dword = quad)
#pragma unroll
        for (int rt = 0; rt < 2; ++rt) {
            const int row = rt * 16 + lr;  // batch row in strip
            v4f a = am[ct][rt];
            unsigned pm = (unsigned)cvt_e4m3(fast_tanh(a[0] + bbm.x))
                        | ((unsigned)cvt_e4m3(fast_tanh(a[1] + bbm.y)) << 8)
                        | ((unsigned)cvt_e4m3(fast_tanh(a[2] + bbm.z)) << 16)
                        | ((unsigned)cvt_e4m3(fast_tanh(a[3] + bbm.w)) << 24);
            v4f b = av[ct][rt];
            unsigned pv = (unsigned)cvt_e4m3(fast_tanh(b[0] + bbv.x))
                        | ((unsigned)cvt_e4m3(fast_tanh(b[1] + bbv.y)) << 8)
                        | ((unsigned)cvt_e4m3(fast_tanh(b[2] + bbv.z)) << 16)
                        | ((unsigned)cvt_e4m3(fast_tanh(b[3] + bbv.w)) << 24);
            const int off = row * 768 + ((cc ^ (row & 15)) << 4) + quad * 4;
            *(unsigned*)&Hm[off] = pm;
            *(unsigned*)&Xs[off] = pv;
        }
    }
    __syncthreads();

    // ---- phase 4: layer-2 dual-branch K-loop (h1 frags from LDS)
    v4f cm[2][3] = {}, cv[2][3] = {};      // [rt][ct]; D-row=batch(quad*4+r), D-col=hidden(lr)
    {
        const unsigned char* __restrict__ pWm = W2m8 + (size_t)(wc0 + lr) * Hn + quad * 16;
        const unsigned char* __restrict__ pWv = W2v8 + (size_t)(wc0 + lr) * Hn + quad * 16;
#pragma unroll
        for (int ms = 0; ms < 12; ++ms) {
            ulonglong2 wmf[3], wvf[3], amf[2], avf[2];
#pragma unroll
            for (int ct = 0; ct < 3; ++ct) {
                wmf[ct] = *(const ulonglong2*)(pWm + ct * (16 * Hn) + ms * 64);
                wvf[ct] = *(const ulonglong2*)(pWv + ct * (16 * Hn) + ms * 64);
            }
#pragma unroll
            for (int rt = 0; rt < 2; ++rt) {
                const int row_ = rt * 16 + lr;
                const int k_ = ms * 4 + quad;
                const int off_ = row_ * 768 + ((k_ ^ (row_ & 15)) << 4);
                amf[rt] = *(const ulonglong2*)&Hm[off_];
                avf[rt] = *(const ulonglong2*)&Xs[off_];
            }
#pragma unroll
            for (int rt = 0; rt < 2; ++rt)
#pragma unroll
                for (int ct = 0; ct < 3; ++ct) {
                    cm[rt][ct] = __builtin_amdgcn_mfma_f32_16x16x32_fp8_fp8((long)amf[rt].x, (long)wmf[ct].x, cm[rt][ct], 0, 0, 0);
                    cv[rt][ct] = __builtin_amdgcn_mfma_f32_16x16x32_fp8_fp8((long)avf[rt].x, (long)wvf[ct].x, cv[rt][ct], 0, 0, 0);
                }
#pragma unroll
            for (int rt = 0; rt < 2; ++rt)
#pragma unroll
                for (int ct = 0; ct < 3; ++ct) {
                    cm[rt][ct] = __builtin_amdgcn_mfma_f32_16x16x32_fp8_fp8((long)amf[rt].y, (long)wmf[ct].y, cm[rt][ct], 0, 0, 0);
                    cv[rt][ct] = __builtin_amdgcn_mfma_f32_16x16x32_fp8_fp8((long)avf[rt].y, (long)wvf[ct].y, cv[rt][ct], 0, 0, 0);
                }
        }
    }

    // ---- phase 5: CLUB epilogue: col = wc0+ct*16+lr, row = strip0+rt*16+quad*4+r
    float pos = 0.f, q = 0.f;   // pos = sum iv*(mu-mb)^2 ; q = sum iv*mu^2
#pragma unroll
    for (int ct = 0; ct < 3; ++ct) {
        const int col = wc0 + ct * 16 + lr;
        const float bmc = b2m[col], bvc = b2v[col];
        float c1 = 0.f, c2 = 0.f, c3 = 0.f, c4 = 0.f;
#pragma unroll
        for (int rt = 0; rt < 2; ++rt) {
#pragma unroll
            for (int r = 0; r < 4; ++r) {
                const int row = strip0 + rt * 16 + quad * 4 + r;
                float mu = cm[rt][ct][r] + bmc;
                float tv = fast_tanh(cv[rt][ct][r] + bvc);
                float iv = __expf(-tv);
                float mbv = mb[(size_t)row * Hn + col];
                float d = mu - mbv;
                pos += iv * d * d;
                q   += iv * mu * mu;
                c1 += mu; c2 += mu * mu; c3 += iv; c4 += iv * mu;
            }
        }
        c1 += __shfl_xor(c1, 16); c1 += __shfl_xor(c1, 32);
        c2 += __shfl_xor(c2, 16); c2 += __shfl_xor(c2, 32);
        c3 += __shfl_xor(c3, 16); c3 += __shfl_xor(c3, 32);
        c4 += __shfl_xor(c4, 16); c4 += __shfl_xor(c4, 32);
        if (quad == 0) {
            atomicAdd(&cs[col], c1);
            atomicAdd(&cs2[col], c2);
            atomicAdd(&siv[col], c3);
            atomicAdd(&sivmu[col], c4);
        }
    }
    for (int off = 32; off > 0; off >>= 1) {
        pos += __shfl_down(pos, off);
        q   += __shfl_down(q, off);
    }
    __shared__ float redP[16], redQ[16];
    if (lane == 0) { redP[w] = pos; redQ[w] = q; }
    __syncthreads();
    __shared__ int is_last;
    if (t == 0) {
        float sp = 0.f, sq = 0.f;
#pragma unroll
        for (int i = 0; i < 16; ++i) { sp += redP[i]; sq += redQ[i]; }
        atomicAdd(&accum[0], sp);
        atomicAdd(&accum[1], sq);
        __threadfence();
        unsigned old = atomicAdd((unsigned int*)&accum[3], 1u);
        is_last = (old == gridDim.x - 1) ? 1 : 0;
    }
    __syncthreads();
    if (is_last) {
        float term = 0.f;
        for (int h = t; h < Hn; h += 1024) {
            float v1 = atomicAdd(&cs[h], 0.0f);
            float v2 = atomicAdd(&cs2[h], 0.0f);
            float v3 = atomicAdd(&siv[h], 0.0f);
            float v4 = atomicAdd(&sivmu[h], 0.0f);
            term += v3 * v2 - 2.0f * v4 * v1;
        }
        for (int off = 32; off > 0; off >>= 1) term += __shfl_down(term, off);
        __shared__ float redT[16];
        if (lane == 0) redT[w] = term;
        __syncthreads();
        if (t == 0) {
            float T = 0.f;
#pragma unroll
            for (int i = 0; i < 16; ++i) T += redT[i];
            float P = atomicAdd(&accum[0], 0.0f);
            float Q = atomicAdd(&accum[1], 0.0f);
            float pos_sum = -0.5f * P;
            float neg_sum = -0.5f * (T * invB + Q);
            outp[0] = pos_sum * invB;
            outp[1] = (pos_sum - neg_sum) * invB;
        }
    }
}

extern "C" void kernel_launch(void* const* d_in, const int* in_sizes, int n_in,
                              void* d_out, int out_size, void* d_ws, size_t ws_size,
                              hipStream_t stream) {
    const float* modal_a = (const float*)d_in[0];
    const float* modal_b = (const float*)d_in[1];
    const float* W1m = (const float*)d_in[2];
    const float* b1m = (const float*)d_in[3];
    const float* W2m = (const float*)d_in[4];
    const float* b2m = (const float*)d_in[5];
    const float* W1v = (const float*)d_in[6];
    const float* b1v = (const float*)d_in[7];
    const float* W2v = (const float*)d_in[8];
    const float* b2v = (const float*)d_in[9];
    float* out = (float*)d_out;

    char* ws = (char*)d_ws;
    constexpr size_t szW8 = (size_t)Hn * Hn;       // fp8 [H,H] = 0.59 MB
    unsigned char* W1m_f8 = (unsigned char*)(ws);
    unsigned char* W2m_f8 = (unsigned char*)(ws + szW8);
    unsigned char* W1v_f8 = (unsigned char*)(ws + 2 * szW8);
    unsigned char* W2v_f8 = (unsigned char*)(ws + 3 * szW8);
    float* cs     = (float*)(ws + 4 * szW8);
    float* cs2    = cs + Hn;
    float* siv    = cs + 2 * Hn;
    float* sivmu  = cs + 3 * Hn;
    float* accum  = cs + 4 * Hn;   // [0]=P [1]=Q [2]=pad [3]=ticket

    void* args[] = { (void*)&modal_a, (void*)&modal_b,
                     (void*)&W1m, (void*)&W2m, (void*)&W1v, (void*)&W2v,
                     (void*)&b1m, (void*)&b1v, (void*)&b2m, (void*)&b2v,
                     (void*)&W1m_f8, (void*)&W2m_f8, (void*)&W1v_f8, (void*)&W2v_f8,
                     (void*)&cs, (void*)&cs2, (void*)&siv, (void*)&sivmu,
                     (void*)&accum, (void*)&out };

    // ONE cooperative launch: prep (grid-wide) + sync + fused MLP/CLUB
    hipLaunchCooperativeKernel((const void*)club_all, dim3(Bn / 32), dim3(1024),
                               args, 0, stream);
}

// Round 7
// 199.193 us; speedup vs baseline: 1.5188x; 1.5188x over previous
//
#include <hip/hip_runtime.h>
#include <hip/hip_fp8.h>
#include <math.h>

typedef float v4f __attribute__((ext_vector_type(4)));

#define AS1 __attribute__((address_space(1)))
#define AS3 __attribute__((address_space(3)))

static constexpr int Bn = 8192;   // batch
static constexpr int Hn = 768;    // hidden
static constexpr float invB = 1.0f / 8192.0f;

__device__ __forceinline__ unsigned char cvt_e4m3(float x) {
    __hip_fp8_e4m3 t(x);          // OCP e4m3fn, RNE + satfinite
    return t.__x;
}

__device__ __forceinline__ unsigned pack4_e4m3(v4f f) {
    return (unsigned)cvt_e4m3(f.x)
         | ((unsigned)cvt_e4m3(f.y) << 8)
         | ((unsigned)cvt_e4m3(f.z) << 16)
         | ((unsigned)cvt_e4m3(f.w) << 24);
}

// tanh(x) = 1 - 2/(exp(2x)+1)
__device__ __forceinline__ float fast_tanh(float x) {
    float xc = fminf(fmaxf(x, -15.0f), 15.0f);
    float e = __expf(2.0f * xc);
    float r = __builtin_amdgcn_rcpf(e + 1.0f);
    return 1.0f - 2.0f * r;
}

// ---------------- prep: zero accumulators + fp32->fp8 the 4 weight matrices ----------------
__global__ void prep_w(const float* __restrict__ W1m, const float* __restrict__ W2m,
                       const float* __restrict__ W1v, const float* __restrict__ W2v,
                       unsigned char* __restrict__ W1m_f8, unsigned char* __restrict__ W2m_f8,
                       unsigned char* __restrict__ W1v_f8, unsigned char* __restrict__ W2v_f8,
                       float* __restrict__ zbuf, int nzero) {
    const int tid = blockIdx.x * blockDim.x + threadIdx.x;
    if (tid < nzero) zbuf[tid] = 0.0f;
    constexpr int W4 = Hn * Hn / 4;    // 4-elem units
    const int total = 4 * W4;
    const int stride = gridDim.x * blockDim.x;
    for (int i = tid; i < total; i += stride) {
        int w = i / W4, j = i - w * W4;
        const float* s = (w == 0) ? W1m : (w == 1) ? W2m : (w == 2) ? W1v : W2v;
        unsigned char* d = (w == 0) ? W1m_f8 : (w == 1) ? W2m_f8 : (w == 2) ? W1v_f8 : W2v_f8;
        v4f v = __builtin_nontemporal_load((const v4f*)s + j);   // read-once: don't pollute L2
        ((unsigned*)d)[j] = pack4_e4m3(v);
    }
}

// ============================================================================
// Fused per-strip kernel, round-6: R4 body + W-L2-residency protection.
//   - A loads NON-TEMPORAL (read-once; keep W resident in per-XCD L2)
//   - mb prestaged into 96 KB LDS via global_load_lds, issued after phase 1,
//     landed by the post-phase-2 __syncthreads vmcnt drain; phase 5 reads LDS
//   256 blocks x 1024 thr, 32-row strip, wave owns 48 hidden cols.
// ============================================================================
__launch_bounds__(1024, 4)
__global__ void club_fused(const float* __restrict__ A_g,
                           const unsigned char* __restrict__ W1m, const unsigned char* __restrict__ W1v,
                           const unsigned char* __restrict__ W2m, const unsigned char* __restrict__ W2v,
                           const float* __restrict__ b1m, const float* __restrict__ b1v,
                           const float* __restrict__ b2m, const float* __restrict__ b2v,
                           const float* __restrict__ mb,
                           float* __restrict__ cs, float* __restrict__ cs2,
                           float* __restrict__ siv, float* __restrict__ sivmu,
                           float* __restrict__ accum, float* __restrict__ outp) {
    __shared__ __align__(16) unsigned char Hm[32 * 768];   // 24 KB: h1m strip
    __shared__ __align__(16) unsigned char Xs[32 * 768];   // 24 KB: A-fp8, then h1v
    __shared__ __align__(16) float Mb_s[32 * 768];         // 96 KB: mb strip (fp32)
    const int t = threadIdx.x;
    const int strip0 = blockIdx.x * 32;    // batch strip

    // ---- phase 1: stage + convert A strip (32 x 768 fp32 -> fp8), 1536 16B chunks
    for (int c = t; c < 1536; c += 1024) {
        const int row = c / 48, cc = c - row * 48;
        const v4f* src = (const v4f*)(A_g + (size_t)(strip0 + row) * Hn + cc * 16);
        v4f f0 = __builtin_nontemporal_load(src + 0);
        v4f f1 = __builtin_nontemporal_load(src + 1);
        v4f f2 = __builtin_nontemporal_load(src + 2);
        v4f f3 = __builtin_nontemporal_load(src + 3);
        uint4 p;
        p.x = pack4_e4m3(f0); p.y = pack4_e4m3(f1);
        p.z = pack4_e4m3(f2); p.w = pack4_e4m3(f3);
        *(uint4*)&Xs[row * 768 + ((cc ^ (row & 15)) << 4)] = p;
    }
    __syncthreads();

    const int w = t >> 6, lane = t & 63;
    const int lr = lane & 15, quad = lane >> 4;
    const int wc0 = w * 48;                // wave's 48 hidden cols

    // ---- issue mb strip -> LDS (96 KB, 6 x 1KB DMA per wave); lands under phase 2,
    //      guaranteed complete by the post-phase-2 __syncthreads (vmcnt drain)
    {
        const char* mb_base = (const char*)(mb + (size_t)strip0 * Hn);
        char* mb_lds = (char*)Mb_s;
#pragma unroll
        for (int j = 0; j < 6; ++j) {
            const int chunk = w * 6 + j;   // 96 chunks x 1024 B
            __builtin_amdgcn_global_load_lds(
                (const AS1 void*)(mb_base + chunk * 1024 + lane * 16),
                (AS3 void*)(mb_lds + chunk * 1024 + lane * 16), 16, 0, 0);
        }
    }

    // ---- phase 2: layer-1 dual-branch K-loop
    v4f am[3][2] = {}, av[3][2] = {};      // [ct][rt]; D-row=hidden(quad*4+r), D-col=batch(lr)
    {
        const unsigned char* __restrict__ pWm = W1m + (size_t)(wc0 + lr) * Hn + quad * 16;
        const unsigned char* __restrict__ pWv = W1v + (size_t)(wc0 + lr) * Hn + quad * 16;
#pragma unroll
        for (int ms = 0; ms < 12; ++ms) {
            ulonglong2 wmf[3], wvf[3], af[2];
#pragma unroll
            for (int ct = 0; ct < 3; ++ct) {
                wmf[ct] = *(const ulonglong2*)(pWm + ct * (16 * Hn) + ms * 64);
                wvf[ct] = *(const ulonglong2*)(pWv + ct * (16 * Hn) + ms * 64);
            }
#pragma unroll
            for (int rt = 0; rt < 2; ++rt) {
                const int row_ = rt * 16 + lr;
                const int k_ = ms * 4 + quad;
                af[rt] = *(const ulonglong2*)&Xs[row_ * 768 + ((k_ ^ (row_ & 15)) << 4)];
            }
#pragma unroll
            for (int ct = 0; ct < 3; ++ct)
#pragma unroll
                for (int rt = 0; rt < 2; ++rt) {
                    am[ct][rt] = __builtin_amdgcn_mfma_f32_16x16x32_fp8_fp8((long)wmf[ct].x, (long)af[rt].x, am[ct][rt], 0, 0, 0);
                    av[ct][rt] = __builtin_amdgcn_mfma_f32_16x16x32_fp8_fp8((long)wvf[ct].x, (long)af[rt].x, av[ct][rt], 0, 0, 0);
                }
#pragma unroll
            for (int ct = 0; ct < 3; ++ct)
#pragma unroll
                for (int rt = 0; rt < 2; ++rt) {
                    am[ct][rt] = __builtin_amdgcn_mfma_f32_16x16x32_fp8_fp8((long)wmf[ct].y, (long)af[rt].y, am[ct][rt], 0, 0, 0);
                    av[ct][rt] = __builtin_amdgcn_mfma_f32_16x16x32_fp8_fp8((long)wvf[ct].y, (long)af[rt].y, av[ct][rt], 0, 0, 0);
                }
        }
    }

    __syncthreads();   // all waves done reading Xs (A); also drains mb DMA (vmcnt 0)

    // ---- phase 3: tanh + fp8 pack -> Hm (mu), Xs (logvar)
#pragma unroll
    for (int ct = 0; ct < 3; ++ct) {
        const float4 bbm = *(const float4*)&b1m[wc0 + ct * 16 + quad * 4];
        const float4 bbv = *(const float4*)&b1v[wc0 + ct * 16 + quad * 4];
        const int cc = w * 3 + ct;         // 16B chunk of these 4 hidden cols (dword = quad)
#pragma unroll
        for (int rt = 0; rt < 2; ++rt) {
            const int row = rt * 16 + lr;  // batch row in strip
            v4f a = am[ct][rt];
            unsigned pm = (unsigned)cvt_e4m3(fast_tanh(a[0] + bbm.x))
                        | ((unsigned)cvt_e4m3(fast_tanh(a[1] + bbm.y)) << 8)
                        | ((unsigned)cvt_e4m3(fast_tanh(a[2] + bbm.z)) << 16)
                        | ((unsigned)cvt_e4m3(fast_tanh(a[3] + bbm.w)) << 24);
            v4f b = av[ct][rt];
            unsigned pv = (unsigned)cvt_e4m3(fast_tanh(b[0] + bbv.x))
                        | ((unsigned)cvt_e4m3(fast_tanh(b[1] + bbv.y)) << 8)
                        | ((unsigned)cvt_e4m3(fast_tanh(b[2] + bbv.z)) << 16)
                        | ((unsigned)cvt_e4m3(fast_tanh(b[3] + bbv.w)) << 24);
            const int off = row * 768 + ((cc ^ (row & 15)) << 4) + quad * 4;
            *(unsigned*)&Hm[off] = pm;
            *(unsigned*)&Xs[off] = pv;
        }
    }
    __syncthreads();

    // ---- phase 4: layer-2 dual-branch K-loop (h1 frags from LDS)
    v4f cm[2][3] = {}, cv[2][3] = {};      // [rt][ct]; D-row=batch(quad*4+r), D-col=hidden(lr)
    {
        const unsigned char* __restrict__ pWm = W2m + (size_t)(wc0 + lr) * Hn + quad * 16;
        const unsigned char* __restrict__ pWv = W2v + (size_t)(wc0 + lr) * Hn + quad * 16;
#pragma unroll
        for (int ms = 0; ms < 12; ++ms) {
            ulonglong2 wmf[3], wvf[3], amf[2], avf[2];
#pragma unroll
            for (int ct = 0; ct < 3; ++ct) {
                wmf[ct] = *(const ulonglong2*)(pWm + ct * (16 * Hn) + ms * 64);
                wvf[ct] = *(const ulonglong2*)(pWv + ct * (16 * Hn) + ms * 64);
            }
#pragma unroll
            for (int rt = 0; rt < 2; ++rt) {
                const int row_ = rt * 16 + lr;
                const int k_ = ms * 4 + quad;
                const int off_ = row_ * 768 + ((k_ ^ (row_ & 15)) << 4);
                amf[rt] = *(const ulonglong2*)&Hm[off_];
                avf[rt] = *(const ulonglong2*)&Xs[off_];
            }
#pragma unroll
            for (int rt = 0; rt < 2; ++rt)
#pragma unroll
                for (int ct = 0; ct < 3; ++ct) {
                    cm[rt][ct] = __builtin_amdgcn_mfma_f32_16x16x32_fp8_fp8((long)amf[rt].x, (long)wmf[ct].x, cm[rt][ct], 0, 0, 0);
                    cv[rt][ct] = __builtin_amdgcn_mfma_f32_16x16x32_fp8_fp8((long)avf[rt].x, (long)wvf[ct].x, cv[rt][ct], 0, 0, 0);
                }
#pragma unroll
            for (int rt = 0; rt < 2; ++rt)
#pragma unroll
                for (int ct = 0; ct < 3; ++ct) {
                    cm[rt][ct] = __builtin_amdgcn_mfma_f32_16x16x32_fp8_fp8((long)amf[rt].y, (long)wmf[ct].y, cm[rt][ct], 0, 0, 0);
                    cv[rt][ct] = __builtin_amdgcn_mfma_f32_16x16x32_fp8_fp8((long)avf[rt].y, (long)wvf[ct].y, cv[rt][ct], 0, 0, 0);
                }
        }
    }

    // ---- phase 5: CLUB epilogue: col = wc0+ct*16+lr, lrow = rt*16+quad*4+r (mb from LDS)
    float pos = 0.f, q = 0.f;   // pos = sum iv*(mu-mb)^2 ; q = sum iv*mu^2
#pragma unroll
    for (int ct = 0; ct < 3; ++ct) {
        const int col = wc0 + ct * 16 + lr;
        const float bmc = b2m[col], bvc = b2v[col];
        float c1 = 0.f, c2 = 0.f, c3 = 0.f, c4 = 0.f;
#pragma unroll
        for (int rt = 0; rt < 2; ++rt) {
#pragma unroll
            for (int r = 0; r < 4; ++r) {
                const int lrow = rt * 16 + quad * 4 + r;
                float mu = cm[rt][ct][r] + bmc;
                float tv = fast_tanh(cv[rt][ct][r] + bvc);
                float iv = __expf(-tv);
                float mbv = Mb_s[lrow * 768 + col];
                float d = mu - mbv;
                pos += iv * d * d;
                q   += iv * mu * mu;
                c1 += mu; c2 += mu * mu; c3 += iv; c4 += iv * mu;
            }
        }
        c1 += __shfl_xor(c1, 16); c1 += __shfl_xor(c1, 32);
        c2 += __shfl_xor(c2, 16); c2 += __shfl_xor(c2, 32);
        c3 += __shfl_xor(c3, 16); c3 += __shfl_xor(c3, 32);
        c4 += __shfl_xor(c4, 16); c4 += __shfl_xor(c4, 32);
        if (quad == 0) {
            atomicAdd(&cs[col], c1);
            atomicAdd(&cs2[col], c2);
            atomicAdd(&siv[col], c3);
            atomicAdd(&sivmu[col], c4);
        }
    }
    for (int off = 32; off > 0; off >>= 1) {
        pos += __shfl_down(pos, off);
        q   += __shfl_down(q, off);
    }
    __shared__ float redP[16], redQ[16];
    if (lane == 0) { redP[w] = pos; redQ[w] = q; }
    __syncthreads();
    __shared__ int is_last;
    if (t == 0) {
        float sp = 0.f, sq = 0.f;
#pragma unroll
        for (int i = 0; i < 16; ++i) { sp += redP[i]; sq += redQ[i]; }
        atomicAdd(&accum[0], sp);
        atomicAdd(&accum[1], sq);
        __threadfence();
        unsigned old = atomicAdd((unsigned int*)&accum[3], 1u);
        is_last = (old == gridDim.x - 1) ? 1 : 0;
    }
    __syncthreads();
    if (is_last) {
        float term = 0.f;
        for (int h = t; h < Hn; h += 1024) {
            float v1 = atomicAdd(&cs[h], 0.0f);
            float v2 = atomicAdd(&cs2[h], 0.0f);
            float v3 = atomicAdd(&siv[h], 0.0f);
            float v4 = atomicAdd(&sivmu[h], 0.0f);
            term += v3 * v2 - 2.0f * v4 * v1;
        }
        for (int off = 32; off > 0; off >>= 1) term += __shfl_down(term, off);
        __shared__ float redT[16];
        if (lane == 0) redT[w] = term;
        __syncthreads();
        if (t == 0) {
            float T = 0.f;
#pragma unroll
            for (int i = 0; i < 16; ++i) T += redT[i];
            float P = atomicAdd(&accum[0], 0.0f);
            float Q = atomicAdd(&accum[1], 0.0f);
            float pos_sum = -0.5f * P;
            float neg_sum = -0.5f * (T * invB + Q);
            outp[0] = pos_sum * invB;
            outp[1] = (pos_sum - neg_sum) * invB;
        }
    }
}

extern "C" void kernel_launch(void* const* d_in, const int* in_sizes, int n_in,
                              void* d_out, int out_size, void* d_ws, size_t ws_size,
                              hipStream_t stream) {
    const float* modal_a = (const float*)d_in[0];
    const float* modal_b = (const float*)d_in[1];
    const float* W1m = (const float*)d_in[2];
    const float* b1m = (const float*)d_in[3];
    const float* W2m = (const float*)d_in[4];
    const float* b2m = (const float*)d_in[5];
    const float* W1v = (const float*)d_in[6];
    const float* b1v = (const float*)d_in[7];
    const float* W2v = (const float*)d_in[8];
    const float* b2v = (const float*)d_in[9];
    float* out = (float*)d_out;

    char* ws = (char*)d_ws;
    constexpr size_t szW8 = (size_t)Hn * Hn;       // fp8 [H,H] = 0.59 MB
    unsigned char* W1m_f8 = (unsigned char*)(ws);
    unsigned char* W2m_f8 = (unsigned char*)(ws + szW8);
    unsigned char* W1v_f8 = (unsigned char*)(ws + 2 * szW8);
    unsigned char* W2v_f8 = (unsigned char*)(ws + 3 * szW8);
    float* cs     = (float*)(ws + 4 * szW8);
    float* cs2    = cs + Hn;
    float* siv    = cs + 2 * Hn;
    float* sivmu  = cs + 3 * Hn;
    float* accum  = cs + 4 * Hn;   // [0]=P [1]=Q [2]=pad [3]=ticket

    // 1. zero accumulators + fp32->fp8 convert the 4 weight matrices
    prep_w<<<576, 256, 0, stream>>>(W1m, W2m, W1v, W2v,
                                    W1m_f8, W2m_f8, W1v_f8, W2v_f8,
                                    cs, 4 * Hn + 8);

    // 2. fused per-strip MLP + CLUB (256 blocks, 16 waves, 32-row strips)
    club_fused<<<dim3(Bn / 32), 1024, 0, stream>>>(
        modal_a, W1m_f8, W1v_f8, W2m_f8, W2v_f8,
        b1m, b1v, b2m, b2v, modal_b,
        cs, cs2, siv, sivmu, accum, out);
}